// Round 6
// baseline (319.167 us; speedup 1.0000x reference)
//
#include <hip/hip_runtime.h>
#include <math.h>

#define IMGN 32
#define HT 1024
#define WD 1024
#define IMG_STRIDE (HT*WD)
#define LOSS_THR_F 120.0f
#define MMX_BLOCKS 4096

// LDS tile layout: dsh[s][i][p], i-stride 68 floats (272B = 17*16B: keeps
// 16B alignment for float4 ops and rotates bank groups across images).
// s-stride 32*68+8 keeps sub-block bank rotation. Per-wave b128 traffic is
// bank-balanced (8 dwords/bank/wave-op = minimum).
#define IST 68
#define SST (32*IST + 8)

typedef float f4nt __attribute__((ext_vector_type(4)));

// ---------------- pass 1: global min/max of width-deltas ----------------
__global__ __launch_bounds__(256) void k_minmax(const float* __restrict__ x,
                                                float* __restrict__ wsf){
  const int lane = threadIdx.x & 63;
  const int wave_id = (blockIdx.x*256 + threadIdx.x) >> 6;   // 0..16383
  const float4* x4 = (const float4*)x;
  const int base4 = wave_id * 512;        // 512 float4 = 2048 floats = 2 rows

  float4 v[8];
  #pragma unroll
  for (int j = 0; j < 8; ++j) v[j] = x4[base4 + j*64 + lane];

  float lmin = INFINITY, lmax = -INFINITY;
  #pragma unroll
  for (int j = 0; j < 8; ++j){
    float lf = __shfl_up(v[j].w, 1);
    float carry = (j == 0 || j == 4) ? 0.0f : __shfl(v[j-1].w, 63);
    if (lane == 0) lf = carry;
    float d0 = v[j].x - lf,      d1 = v[j].y - v[j].x;
    float d2 = v[j].z - v[j].y,  d3 = v[j].w - v[j].z;
    lmin = fminf(lmin, fminf(fminf(d0, d1), fminf(d2, d3)));
    lmax = fmaxf(lmax, fmaxf(fmaxf(d0, d1), fmaxf(d2, d3)));
  }
  #pragma unroll
  for (int off = 32; off; off >>= 1){
    lmin = fminf(lmin, __shfl_xor(lmin, off));
    lmax = fmaxf(lmax, __shfl_xor(lmax, off));
  }
  __shared__ float smin[4], smax[4];
  int wv = threadIdx.x >> 6;
  if (lane == 0){ smin[wv] = lmin; smax[wv] = lmax; }
  __syncthreads();
  if (threadIdx.x == 0){
    wsf[2*blockIdx.x]   = fminf(fminf(smin[0], smin[1]), fminf(smin[2], smin[3]));
    wsf[2*blockIdx.x+1] = fmaxf(fmaxf(smax[0], smax[1]), fmaxf(smax[2], smax[3]));
  }
}

// ---------------- pass 2: per-8x8-block fit + output ----------------
// one 256-thread WG per (8 rows x 16 cols x 32 imgs) tile = 2 sub-blocks.
// 17.6KB LDS + 256 threads -> up to 8 WGs/CU resident (vs 4 with the old
// 512-thread tile): more independent WGs to hide phase-boundary latency.
// Final min/max reduction of the 4096 partials folded in (L2-hot).
__global__ __launch_bounds__(256, 8) void k_main(const float* __restrict__ x,
                                                 float* __restrict__ out,
                                                 const float* __restrict__ wsf){
  __shared__ __align__(16) float dsh[2*SST];
  __shared__ float s_inv[2][9];
  __shared__ int   s_degen[2];
  __shared__ float smm[8];

  const int tid = threadIdx.x;
  const int bid = blockIdx.x;
  const int xcd = bid & 7;               // 8192 blocks: bijective swizzle
  const int jj  = bid >> 3;              // 0..1023
  const int hb  = xcd*16 + (jj >> 6);    // 0..127 row-blocks
  const int cb2 = jj & 63;               // 0..63 col-tiles of 16
  const int row0 = hb << 3;
  const int col0 = cb2 << 4;

  // ---- k-invariant index decomposition (f = tid + 256k) ----
  const int rem = tid & 31;
  const int r   = rem >> 2;          // row within 8-row tile
  const int fi  = rem & 3;           // float4 within 16-col tile
  const int i0  = tid >> 5;          // image 0..7 (+8k)
  const int sB0 = fi >> 1;           // sub-block of this lane's float4
  const int p1  = (r << 3) + ((fi & 1) << 2);   // pixel base, mult of 4
  const int lbase0 = sB0*SST + i0*IST + p1;     // +8*IST per k
  const int gc0 = col0 + (fi << 2);
  const size_t elt0 = (size_t)i0*IMG_STRIDE + (size_t)(row0+r)*WD + gc0;

  // ---- issue ALL x loads first (latency overlaps the minmax fold) ----
  float4 vv[4];
  #pragma unroll
  for (int k = 0; k < 4; ++k)
    vv[k] = *(const float4*)(x + elt0 + (size_t)(k << 3)*IMG_STRIDE);
  float lfe[4] = {0.0f, 0.0f, 0.0f, 0.0f};
  if (fi == 0 && col0){
    #pragma unroll
    for (int k = 0; k < 4; ++k)
      lfe[k] = x[elt0 + (size_t)(k << 3)*IMG_STRIDE - 1];
  }

  // ---- folded k_reduce: all threads reduce the 4096 partials ----
  float mnP = INFINITY, mxP = -INFINITY;
  {
    const float2* w2 = (const float2*)wsf;
    #pragma unroll
    for (int j = 0; j < 16; ++j){
      float2 p = w2[tid + (j << 8)];
      mnP = fminf(mnP, p.x); mxP = fmaxf(mxP, p.y);
    }
    #pragma unroll
    for (int off = 32; off; off >>= 1){
      mnP = fminf(mnP, __shfl_xor(mnP, off));
      mxP = fmaxf(mxP, __shfl_xor(mxP, off));
    }
    if ((tid & 63) == 0){ smm[tid >> 6] = mnP; smm[4 + (tid >> 6)] = mxP; }
  }
  __syncthreads();
  const float mn = fminf(fminf(smm[0], smm[1]), fminf(smm[2], smm[3]));
  const float mx = fmaxf(fmaxf(smm[4], smm[5]), fmaxf(smm[6], smm[7]));

  const bool  neq = (mx != mn);
  const float scale = neq ? (65535.0f / (mx - mn)) : 1.0f;
  const float sinv  = 1.0f / scale;
  const float moff  = neq ? mn : 0.0f;
  // lsb is an exact power of 2 -> division by it == multiplication by ilsb
  const float e1   = rintf(log2f(mx * (1.0f/32768.0f))) + 1.0f;
  const float lsb  = exp2f(e1);
  const float ilsb = exp2f(-e1);

  // ---- phase 1: delta + quantize/dequant -> dsh (1 b128 per k).
  // lanes are 4-per-row: for fi!=0 the left neighbor is lane-1's v.w
  // (same row); fi==0 lanes use the pre-loaded edge value.
  float4 keep[4];
  #pragma unroll
  for (int k = 0; k < 4; ++k){
    float4 v = vv[k];
    float lf = __shfl_up(v.w, 1);
    if (fi == 0) lf = lfe[k];
    keep[k] = make_float4(lf, v.x, v.y, v.z);
    float d0 = v.x - lf, d1 = v.y - v.x, d2 = v.z - v.y, d3 = v.w - v.z;
    float q0, q1, q2, q3;
    if (neq){
      q0 = __fadd_rn(__fmul_rn(rintf((d0 - mn) * scale), sinv), moff);
      q1 = __fadd_rn(__fmul_rn(rintf((d1 - mn) * scale), sinv), moff);
      q2 = __fadd_rn(__fmul_rn(rintf((d2 - mn) * scale), sinv), moff);
      q3 = __fadd_rn(__fmul_rn(rintf((d3 - mn) * scale), sinv), moff);
    } else { q0 = d0; q1 = d1; q2 = d2; q3 = d3; }
    *(float4*)(dsh + lbase0 + k*(8*IST)) = make_float4(q0, q1, q2, q3);
  }
  __syncthreads();

  // ---- phase 2: 3x3 normal matrix per sub-block (wave w -> sub-block w)
  if (tid < 128){
    int s = tid >> 6;                    // 0..1
    int p = tid & 63;
    float a0 = dsh[s*SST + 0*IST + p];   // image 0, pixel p (conflict-free)
    float a1 = dsh[s*SST + 1*IST + p];   // image 1, pixel p
    double s00 = (double)a0*a0, s01 = (double)a0*a1, s02 = a0;
    double s11 = (double)a1*a1, s12 = a1;
    float mx0 = a0, mn0 = a0, mx1 = a1, mn1 = a1;
    #pragma unroll
    for (int off = 32; off; off >>= 1){
      s00 += __shfl_xor(s00, off);
      s01 += __shfl_xor(s01, off);
      s02 += __shfl_xor(s02, off);
      s11 += __shfl_xor(s11, off);
      s12 += __shfl_xor(s12, off);
      mx0 = fmaxf(mx0, __shfl_xor(mx0, off));
      mn0 = fminf(mn0, __shfl_xor(mn0, off));
      mx1 = fmaxf(mx1, __shfl_xor(mx1, off));
      mn1 = fminf(mn1, __shfl_xor(mn1, off));
    }
    if (p == 0){
      double a = (float)s00, b = (float)s01, c = (float)s02;
      double d = (float)s11, e = (float)s12, f = 64.0;
      double c00 = d*f - e*e;
      double c01 = c*e - b*f;
      double c02 = b*e - c*d;
      double det = a*c00 + b*c01 + c*c02;
      float inv[9];
      if (det == 0.0){
        inv[0]=1.f;inv[1]=0.f;inv[2]=0.f;
        inv[3]=0.f;inv[4]=1.f;inv[5]=0.f;
        inv[6]=0.f;inv[7]=0.f;inv[8]=1.f;
      } else {
        double id = 1.0/det;
        double c11 = a*f - c*c;
        double c12 = b*c - a*e;
        double c22 = a*d - b*b;
        inv[0]=(float)(c00*id); inv[1]=(float)(c01*id); inv[2]=(float)(c02*id);
        inv[3]=inv[1];          inv[4]=(float)(c11*id); inv[5]=(float)(c12*id);
        inv[6]=inv[2];          inv[7]=inv[5];          inv[8]=(float)(c22*id);
      }
      #pragma unroll
      for (int q = 0; q < 9; ++q) s_inv[s][q] = inv[q];
      s_degen[s] = (((mx0 - mn0) < 1e-6f) && ((mx1 - mn1) < 1e-6f)) ? 1 : 0;
    }
  }
  __syncthreads();

  // ---- phase 3: per-image fit; per-k staging (all b128), rr in registers.
  const int i_img = tid >> 3;            // 0..31
  const int sub   = tid & 7;
  const int p0    = sub << 3;

  float dv[2][8];
  #pragma unroll
  for (int k = 0; k < 2; ++k){
    const int sB = k;                    // each thread does both sub-blocks
    const int sb = sB*SST;
    float4 dlo = *(const float4*)(dsh + sb + i_img*IST + p0);
    float4 dhi = *(const float4*)(dsh + sb + i_img*IST + p0 + 4);
    float4 A0l = *(const float4*)(dsh + sb + 0*IST + p0);      // broadcast
    float4 A0h = *(const float4*)(dsh + sb + 0*IST + p0 + 4);
    float4 A1l = *(const float4*)(dsh + sb + 1*IST + p0);
    float4 A1h = *(const float4*)(dsh + sb + 1*IST + p0 + 4);
    float dva[8] = {dlo.x,dlo.y,dlo.z,dlo.w, dhi.x,dhi.y,dhi.z,dhi.w};
    float a0a[8] = {A0l.x,A0l.y,A0l.z,A0l.w, A0h.x,A0h.y,A0h.z,A0h.w};
    float a1a[8] = {A1l.x,A1l.y,A1l.z,A1l.w, A1h.x,A1h.y,A1h.z,A1h.w};

    const float i00 = s_inv[sB][0], i01 = s_inv[sB][1], i02 = s_inv[sB][2];
    const float i10 = s_inv[sB][3], i11 = s_inv[sB][4], i12 = s_inv[sB][5];
    const float i20 = s_inv[sB][6], i21 = s_inv[sB][7], i22 = s_inv[sB][8];

    float pc0 = 0.f, pc1 = 0.f, pc2v = 0.f;
    #pragma unroll
    for (int c2 = 0; c2 < 8; ++c2){
      float b0 = __fadd_rn(__fmaf_rn(i01, a1a[c2], __fmul_rn(i00, a0a[c2])), i02);
      float b1 = __fadd_rn(__fmaf_rn(i11, a1a[c2], __fmul_rn(i10, a0a[c2])), i12);
      float b2 = __fadd_rn(__fmaf_rn(i21, a1a[c2], __fmul_rn(i20, a0a[c2])), i22);
      pc0  = __fmaf_rn(b0, dva[c2], pc0);
      pc1  = __fmaf_rn(b1, dva[c2], pc1);
      pc2v = __fmaf_rn(b2, dva[c2], pc2v);
    }
    pc0  += __shfl_xor(pc0, 1);  pc0  += __shfl_xor(pc0, 2);  pc0  += __shfl_xor(pc0, 4);
    pc1  += __shfl_xor(pc1, 1);  pc1  += __shfl_xor(pc1, 2);  pc1  += __shfl_xor(pc1, 4);
    pc2v += __shfl_xor(pc2v, 1); pc2v += __shfl_xor(pc2v, 2); pc2v += __shfl_xor(pc2v, 4);

    float r1v[8];
    float loss = 0.f;
    #pragma unroll
    for (int c2 = 0; c2 < 8; ++c2){
      float rv = __fadd_rn(__fmaf_rn(a1a[c2], pc1, __fmul_rn(a0a[c2], pc0)), pc2v);
      float r1 = __fmul_rn(rintf(__fmul_rn(rv, ilsb)), lsb);
      r1v[c2] = r1;
      float df = __fsub_rn(dva[c2], r1);
      loss = __fadd_rn(loss, __fmul_rn(df, df));
    }
    loss += __shfl_xor(loss, 1); loss += __shfl_xor(loss, 2); loss += __shfl_xor(loss, 4);
    const bool sel = (!s_degen[sB]) && (loss <= LOSS_THR_F);
    #pragma unroll
    for (int c2 = 0; c2 < 8; ++c2)
      dv[k][c2] = sel ? r1v[c2] : dva[c2];       // rr in registers
  }
  __syncthreads();                               // all reads done everywhere
  #pragma unroll
  for (int k = 0; k < 2; ++k){
    const int sb = k*SST + i_img*IST + p0;
    *(float4*)(dsh + sb)     = make_float4(dv[k][0], dv[k][1], dv[k][2], dv[k][3]);
    *(float4*)(dsh + sb + 4) = make_float4(dv[k][4], dv[k][5], dv[k][6], dv[k][7]);
  }
  __syncthreads();

  // ---- phase 4: coalesced epilogue, x_left from registers, b128 LDS reads,
  // NON-TEMPORAL stores: out is never re-read; keeping it out of L2/L3
  // stops it evicting x (134MB x + 134MB out > 256MB L3 -> thrash).
  #pragma unroll
  for (int k = 0; k < 4; ++k){
    const size_t elt = elt0 + (size_t)(k << 3)*IMG_STRIDE;
    float4 q = *(const float4*)(dsh + lbase0 + k*(8*IST));
    f4nt o;
    o.x = q.x + keep[k].x;
    o.y = q.y + keep[k].y;
    o.z = q.z + keep[k].z;
    o.w = q.w + keep[k].w;
    __builtin_nontemporal_store(o, (f4nt*)(out + elt));
  }
}

extern "C" void kernel_launch(void* const* d_in, const int* in_sizes, int n_in,
                              void* d_out, int out_size, void* d_ws, size_t ws_size,
                              hipStream_t stream) {
  const float* x = (const float*)d_in[0];
  float* out = (float*)d_out;
  float* wsf = (float*)d_ws;
  hipLaunchKernelGGL(k_minmax, dim3(MMX_BLOCKS), dim3(256), 0, stream, x, wsf);
  hipLaunchKernelGGL(k_main,   dim3(8192),       dim3(256), 0, stream, x, out, wsf);
}

// Round 7
// 283.416 us; speedup vs baseline: 1.1261x; 1.1261x over previous
//
#include <hip/hip_runtime.h>
#include <math.h>

#define IMGN 32
#define HT 1024
#define WD 1024
#define IMG_STRIDE (HT*WD)
#define LOSS_THR_F 120.0f
#define MMX_BLOCKS 4096

// LDS tile layout: dsh[s][i][p], i-stride 68 floats (272B = 17*16B: keeps
// 16B alignment for float4 ops and rotates bank groups across images).
// s-stride 32*68+8: the +8 (32B, keeps 16B alignment) makes the sub-block
// index rotate bank quads (8*s mod 32) -> phase-1 pattern is uniform 2-way
// (free on CDNA4 per m136).
#define IST 68
#define SST (32*IST + 8)

typedef float f4nt __attribute__((ext_vector_type(4)));

// ---------------- pass 1: global min/max of width-deltas ----------------
__global__ __launch_bounds__(256) void k_minmax(const float* __restrict__ x,
                                                float* __restrict__ wsf){
  const int lane = threadIdx.x & 63;
  const int wave_id = (blockIdx.x*256 + threadIdx.x) >> 6;   // 0..16383
  const float4* x4 = (const float4*)x;
  const int base4 = wave_id * 512;        // 512 float4 = 2048 floats = 2 rows

  float4 v[8];
  #pragma unroll
  for (int j = 0; j < 8; ++j) v[j] = x4[base4 + j*64 + lane];

  float lmin = INFINITY, lmax = -INFINITY;
  #pragma unroll
  for (int j = 0; j < 8; ++j){
    float lf = __shfl_up(v[j].w, 1);
    float carry = (j == 0 || j == 4) ? 0.0f : __shfl(v[j-1].w, 63);
    if (lane == 0) lf = carry;
    float d0 = v[j].x - lf,      d1 = v[j].y - v[j].x;
    float d2 = v[j].z - v[j].y,  d3 = v[j].w - v[j].z;
    lmin = fminf(lmin, fminf(fminf(d0, d1), fminf(d2, d3)));
    lmax = fmaxf(lmax, fmaxf(fmaxf(d0, d1), fmaxf(d2, d3)));
  }
  #pragma unroll
  for (int off = 32; off; off >>= 1){
    lmin = fminf(lmin, __shfl_xor(lmin, off));
    lmax = fmaxf(lmax, __shfl_xor(lmax, off));
  }
  __shared__ float smin[4], smax[4];
  int wv = threadIdx.x >> 6;
  if (lane == 0){ smin[wv] = lmin; smax[wv] = lmax; }
  __syncthreads();
  if (threadIdx.x == 0){
    wsf[2*blockIdx.x]   = fminf(fminf(smin[0], smin[1]), fminf(smin[2], smin[3]));
    wsf[2*blockIdx.x+1] = fmaxf(fmaxf(smax[0], smax[1]), fmaxf(smax[2], smax[3]));
  }
}

// ---------------- pass 2: per-8x8-block fit + output ----------------
// one 512-thread WG per (8 rows x 32 cols x 32 imgs) tile = 4 sub-blocks.
// Folded-in final min/max reduce (L2-hot). Normal-matrix fit is computed
// inside phase 3 per 8-lane group (each group holds the whole sub-block
// basis) -> no separate phase-2, 4 barriers total, no idle waves.
// Global traffic: every wave load/store is full 128B lines (the 256-thr /
// 64B-chunk variant wrote 361MB to HBM vs 131MB here -- NT partial lines
// cannot merge; keep 32-col tiles).
__global__ __launch_bounds__(512) void k_main(const float* __restrict__ x,
                                              float* __restrict__ out,
                                              const float* __restrict__ wsf){
  __shared__ __align__(16) float dsh[4*SST];
  __shared__ float smm[16];

  const int tid = threadIdx.x;
  const int bid = blockIdx.x;
  const int xcd = bid & 7;
  const int jj  = bid >> 3;
  const int hb  = xcd*16 + (jj >> 5);
  const int cb  = jj & 31;
  const int row0 = hb << 3;
  const int col0 = cb << 5;

  // ---- k-invariant index decomposition (f = tid + 512k) ----
  const int rem = tid & 63;
  const int r   = rem >> 3;          // row within 8-row tile
  const int fi  = rem & 7;           // float4 within 32-col tile
  const int i0  = tid >> 6;          // image 0..7 (+8k)
  const int sB0 = fi >> 1;           // sub-block of this lane's float4
  const int p1  = (r << 3) + ((fi & 1) << 2);   // pixel base, mult of 4
  const int lbase0 = sB0*SST + i0*IST + p1;     // +8*IST per k
  const int gc0 = col0 + (fi << 2);
  const size_t elt0 = (size_t)i0*IMG_STRIDE + (size_t)(row0+r)*WD + gc0;

  // ---- issue ALL x loads first (latency overlaps the minmax fold) ----
  float4 vv[4];
  #pragma unroll
  for (int k = 0; k < 4; ++k)
    vv[k] = *(const float4*)(x + elt0 + (size_t)(k << 3)*IMG_STRIDE);
  float lfe[4] = {0.0f, 0.0f, 0.0f, 0.0f};
  if (fi == 0 && col0){
    #pragma unroll
    for (int k = 0; k < 4; ++k)
      lfe[k] = x[elt0 + (size_t)(k << 3)*IMG_STRIDE - 1];
  }

  // ---- folded k_reduce: all threads reduce the 4096 partials ----
  float mnP = INFINITY, mxP = -INFINITY;
  {
    const float2* w2 = (const float2*)wsf;
    #pragma unroll
    for (int j = 0; j < 8; ++j){
      float2 p = w2[tid + (j << 9)];
      mnP = fminf(mnP, p.x); mxP = fmaxf(mxP, p.y);
    }
    #pragma unroll
    for (int off = 32; off; off >>= 1){
      mnP = fminf(mnP, __shfl_xor(mnP, off));
      mxP = fmaxf(mxP, __shfl_xor(mxP, off));
    }
    if ((tid & 63) == 0){ smm[tid >> 6] = mnP; smm[8 + (tid >> 6)] = mxP; }
  }
  __syncthreads();
  const float mn = fminf(fminf(fminf(smm[0], smm[1]), fminf(smm[2], smm[3])),
                         fminf(fminf(smm[4], smm[5]), fminf(smm[6], smm[7])));
  const float mx = fmaxf(fmaxf(fmaxf(smm[8], smm[9]), fmaxf(smm[10], smm[11])),
                         fmaxf(fmaxf(smm[12], smm[13]), fmaxf(smm[14], smm[15])));

  const bool  neq = (mx != mn);
  const float scale = neq ? (65535.0f / (mx - mn)) : 1.0f;
  const float sinv  = 1.0f / scale;
  const float moff  = neq ? mn : 0.0f;
  // lsb is an exact power of 2 -> division by it == multiplication by ilsb
  const float e1   = rintf(log2f(mx * (1.0f/32768.0f))) + 1.0f;
  const float lsb  = exp2f(e1);
  const float ilsb = exp2f(-e1);

  // ---- phase 1: delta + quantize/dequant -> dsh (1 b128 per k).
  float4 keep[4];
  #pragma unroll
  for (int k = 0; k < 4; ++k){
    float4 v = vv[k];
    float lf = __shfl_up(v.w, 1);
    if (fi == 0) lf = lfe[k];
    keep[k] = make_float4(lf, v.x, v.y, v.z);
    float d0 = v.x - lf, d1 = v.y - v.x, d2 = v.z - v.y, d3 = v.w - v.z;
    float q0, q1, q2, q3;
    if (neq){
      q0 = __fadd_rn(__fmul_rn(rintf((d0 - mn) * scale), sinv), moff);
      q1 = __fadd_rn(__fmul_rn(rintf((d1 - mn) * scale), sinv), moff);
      q2 = __fadd_rn(__fmul_rn(rintf((d2 - mn) * scale), sinv), moff);
      q3 = __fadd_rn(__fmul_rn(rintf((d3 - mn) * scale), sinv), moff);
    } else { q0 = d0; q1 = d1; q2 = d2; q3 = d3; }
    *(float4*)(dsh + lbase0 + k*(8*IST)) = make_float4(q0, q1, q2, q3);
  }
  __syncthreads();

  // ---- phase 3: per-image fit with in-group normal-matrix solve.
  // 8-lane group (same i_img, sub=0..7) spans all 64 pixels of a sub-block:
  // basis sums via local-8 + 3-level butterfly; 3x3 double inverse computed
  // redundantly per lane (registers, no barrier, no LDS broadcast).
  const int i_img = (tid >> 3) & 31;
  const int sub   = tid & 7;
  const int p0    = sub << 3;

  float dv[2][8];
  int ss[2];
  #pragma unroll
  for (int k = 0; k < 2; ++k){
    const int sB = ((tid >> 8) << 1) + k; ss[k] = sB;
    const int sb = sB*SST;
    // basis staging first (double live-range ends before dva loads)
    float4 A0l = *(const float4*)(dsh + sb + 0*IST + p0);      // broadcast
    float4 A0h = *(const float4*)(dsh + sb + 0*IST + p0 + 4);
    float4 A1l = *(const float4*)(dsh + sb + 1*IST + p0);
    float4 A1h = *(const float4*)(dsh + sb + 1*IST + p0 + 4);
    float a0a[8] = {A0l.x,A0l.y,A0l.z,A0l.w, A0h.x,A0h.y,A0h.z,A0h.w};
    float a1a[8] = {A1l.x,A1l.y,A1l.z,A1l.w, A1h.x,A1h.y,A1h.z,A1h.w};

    // folded phase-2: sums + min/max over the 8-lane group
    double s00 = 0.0, s01 = 0.0, s02 = 0.0, s11 = 0.0, s12 = 0.0;
    float mx0 = a0a[0], mn0 = a0a[0], mx1 = a1a[0], mn1 = a1a[0];
    #pragma unroll
    for (int c2 = 0; c2 < 8; ++c2){
      double A0 = a0a[c2], A1 = a1a[c2];
      s00 += A0*A0; s01 += A0*A1; s02 += A0;
      s11 += A1*A1; s12 += A1;
      mx0 = fmaxf(mx0, a0a[c2]); mn0 = fminf(mn0, a0a[c2]);
      mx1 = fmaxf(mx1, a1a[c2]); mn1 = fminf(mn1, a1a[c2]);
    }
    #pragma unroll
    for (int off = 1; off < 8; off <<= 1){
      s00 += __shfl_xor(s00, off);
      s01 += __shfl_xor(s01, off);
      s02 += __shfl_xor(s02, off);
      s11 += __shfl_xor(s11, off);
      s12 += __shfl_xor(s12, off);
      mx0 = fmaxf(mx0, __shfl_xor(mx0, off));
      mn0 = fminf(mn0, __shfl_xor(mn0, off));
      mx1 = fmaxf(mx1, __shfl_xor(mx1, off));
      mn1 = fminf(mn1, __shfl_xor(mn1, off));
    }
    const bool degen = ((mx0 - mn0) < 1e-6f) && ((mx1 - mn1) < 1e-6f);
    float i00,i01,i02,i10,i11,i12,i20,i21,i22;
    {
      double a = (float)s00, b = (float)s01, c = (float)s02;
      double d = (float)s11, e = (float)s12, f = 64.0;
      double c00 = d*f - e*e;
      double c01 = c*e - b*f;
      double c02 = b*e - c*d;
      double det = a*c00 + b*c01 + c*c02;
      if (det == 0.0){
        i00=1.f;i01=0.f;i02=0.f; i10=0.f;i11=1.f;i12=0.f; i20=0.f;i21=0.f;i22=1.f;
      } else {
        double id = 1.0/det;
        double c11 = a*f - c*c;
        double c12 = b*c - a*e;
        double c22 = a*d - b*b;
        i00=(float)(c00*id); i01=(float)(c01*id); i02=(float)(c02*id);
        i10=i01;             i11=(float)(c11*id); i12=(float)(c12*id);
        i20=i02;             i21=i12;             i22=(float)(c22*id);
      }
    }

    float4 dlo = *(const float4*)(dsh + sb + i_img*IST + p0);
    float4 dhi = *(const float4*)(dsh + sb + i_img*IST + p0 + 4);
    float dva[8] = {dlo.x,dlo.y,dlo.z,dlo.w, dhi.x,dhi.y,dhi.z,dhi.w};

    float pc0 = 0.f, pc1 = 0.f, pc2v = 0.f;
    #pragma unroll
    for (int c2 = 0; c2 < 8; ++c2){
      float b0 = __fadd_rn(__fmaf_rn(i01, a1a[c2], __fmul_rn(i00, a0a[c2])), i02);
      float b1 = __fadd_rn(__fmaf_rn(i11, a1a[c2], __fmul_rn(i10, a0a[c2])), i12);
      float b2 = __fadd_rn(__fmaf_rn(i21, a1a[c2], __fmul_rn(i20, a0a[c2])), i22);
      pc0  = __fmaf_rn(b0, dva[c2], pc0);
      pc1  = __fmaf_rn(b1, dva[c2], pc1);
      pc2v = __fmaf_rn(b2, dva[c2], pc2v);
    }
    pc0  += __shfl_xor(pc0, 1);  pc0  += __shfl_xor(pc0, 2);  pc0  += __shfl_xor(pc0, 4);
    pc1  += __shfl_xor(pc1, 1);  pc1  += __shfl_xor(pc1, 2);  pc1  += __shfl_xor(pc1, 4);
    pc2v += __shfl_xor(pc2v, 1); pc2v += __shfl_xor(pc2v, 2); pc2v += __shfl_xor(pc2v, 4);

    float r1v[8];
    float loss = 0.f;
    #pragma unroll
    for (int c2 = 0; c2 < 8; ++c2){
      float rv = __fadd_rn(__fmaf_rn(a1a[c2], pc1, __fmul_rn(a0a[c2], pc0)), pc2v);
      float r1 = __fmul_rn(rintf(__fmul_rn(rv, ilsb)), lsb);
      r1v[c2] = r1;
      float df = __fsub_rn(dva[c2], r1);
      loss = __fadd_rn(loss, __fmul_rn(df, df));
    }
    loss += __shfl_xor(loss, 1); loss += __shfl_xor(loss, 2); loss += __shfl_xor(loss, 4);
    const bool sel = (!degen) && (loss <= LOSS_THR_F);
    #pragma unroll
    for (int c2 = 0; c2 < 8; ++c2)
      dv[k][c2] = sel ? r1v[c2] : dva[c2];       // rr in registers
  }
  __syncthreads();                               // all reads done everywhere
  #pragma unroll
  for (int k = 0; k < 2; ++k){
    const int sb = ss[k]*SST + i_img*IST + p0;
    *(float4*)(dsh + sb)     = make_float4(dv[k][0], dv[k][1], dv[k][2], dv[k][3]);
    *(float4*)(dsh + sb + 4) = make_float4(dv[k][4], dv[k][5], dv[k][6], dv[k][7]);
  }
  __syncthreads();

  // ---- phase 4: coalesced epilogue, x_left from registers, b128 LDS reads,
  // NON-TEMPORAL stores: out is never re-read; keeping it out of L2/L3
  // stops it evicting x (134MB x + 134MB out > 256MB L3 -> thrash).
  #pragma unroll
  for (int k = 0; k < 4; ++k){
    const size_t elt = elt0 + (size_t)(k << 3)*IMG_STRIDE;
    float4 q = *(const float4*)(dsh + lbase0 + k*(8*IST));
    f4nt o;
    o.x = q.x + keep[k].x;
    o.y = q.y + keep[k].y;
    o.z = q.z + keep[k].z;
    o.w = q.w + keep[k].w;
    __builtin_nontemporal_store(o, (f4nt*)(out + elt));
  }
}

extern "C" void kernel_launch(void* const* d_in, const int* in_sizes, int n_in,
                              void* d_out, int out_size, void* d_ws, size_t ws_size,
                              hipStream_t stream) {
  const float* x = (const float*)d_in[0];
  float* out = (float*)d_out;
  float* wsf = (float*)d_ws;
  hipLaunchKernelGGL(k_minmax, dim3(MMX_BLOCKS), dim3(256), 0, stream, x, wsf);
  hipLaunchKernelGGL(k_main,   dim3(4096),       dim3(512), 0, stream, x, out, wsf);
}

// Round 8
// 262.077 us; speedup vs baseline: 1.2178x; 1.0814x over previous
//
#include <hip/hip_runtime.h>
#include <math.h>

#define IMGN 32
#define HT 1024
#define WD 1024
#define IMG_STRIDE (HT*WD)
#define LOSS_THR_F 120.0f
#define MMX_BLOCKS 4096

// LDS tile layout: dsh[s][i][p], i-stride 68 floats (272B = 17*16B: keeps
// 16B alignment for float4 ops and rotates bank groups across images).
// s-stride 32*68+8: the +8 (32B, keeps 16B alignment) makes the sub-block
// index rotate bank quads (8*s mod 32) -> phase-1 pattern is uniform 2-way
// (free on CDNA4 per m136).
#define IST 68
#define SST (32*IST + 8)
#define BST 68   // s_base row stride (64 + 4 pad, float4-aligned)

typedef float f4nt __attribute__((ext_vector_type(4)));

// ---------------- pass 1: global min/max of width-deltas ----------------
__global__ __launch_bounds__(256) void k_minmax(const float* __restrict__ x,
                                                float* __restrict__ wsf){
  const int lane = threadIdx.x & 63;
  const int wave_id = (blockIdx.x*256 + threadIdx.x) >> 6;   // 0..16383
  const float4* x4 = (const float4*)x;
  const int base4 = wave_id * 512;        // 512 float4 = 2048 floats = 2 rows

  float4 v[8];
  #pragma unroll
  for (int j = 0; j < 8; ++j) v[j] = x4[base4 + j*64 + lane];

  float lmin = INFINITY, lmax = -INFINITY;
  #pragma unroll
  for (int j = 0; j < 8; ++j){
    float lf = __shfl_up(v[j].w, 1);
    float carry = (j == 0 || j == 4) ? 0.0f : __shfl(v[j-1].w, 63);
    if (lane == 0) lf = carry;
    float d0 = v[j].x - lf,      d1 = v[j].y - v[j].x;
    float d2 = v[j].z - v[j].y,  d3 = v[j].w - v[j].z;
    lmin = fminf(lmin, fminf(fminf(d0, d1), fminf(d2, d3)));
    lmax = fmaxf(lmax, fmaxf(fmaxf(d0, d1), fmaxf(d2, d3)));
  }
  #pragma unroll
  for (int off = 32; off; off >>= 1){
    lmin = fminf(lmin, __shfl_xor(lmin, off));
    lmax = fmaxf(lmax, __shfl_xor(lmax, off));
  }
  __shared__ float smin[4], smax[4];
  int wv = threadIdx.x >> 6;
  if (lane == 0){ smin[wv] = lmin; smax[wv] = lmax; }
  __syncthreads();
  if (threadIdx.x == 0){
    wsf[2*blockIdx.x]   = fminf(fminf(smin[0], smin[1]), fminf(smin[2], smin[3]));
    wsf[2*blockIdx.x+1] = fmaxf(fmaxf(smax[0], smax[1]), fmaxf(smax[2], smax[3]));
  }
}

// ---------------- pass 2: per-8x8-block fit + output ----------------
// one 512-thread WG per (8 rows x 32 cols x 32 imgs) tile = 4 sub-blocks.
// Round-5 structure (best verified) + phase-2 now precomputes the
// projection vectors b[3][pixel] per sub-block (they are image-invariant;
// computing them in phase 3 repeated the work 32x across images).
__global__ __launch_bounds__(512) void k_main(const float* __restrict__ x,
                                              float* __restrict__ out,
                                              const float* __restrict__ wsf){
  __shared__ __align__(16) float dsh[4*SST];
  __shared__ __align__(16) float s_base[4*3*BST];
  __shared__ int   s_degen[4];
  __shared__ float smm[16];

  const int tid = threadIdx.x;
  const int bid = blockIdx.x;
  const int xcd = bid & 7;
  const int jj  = bid >> 3;
  const int hb  = xcd*16 + (jj >> 5);
  const int cb  = jj & 31;
  const int row0 = hb << 3;
  const int col0 = cb << 5;

  // ---- k-invariant index decomposition (f = tid + 512k) ----
  const int rem = tid & 63;
  const int r   = rem >> 3;          // row within 8-row tile
  const int fi  = rem & 7;           // float4 within 32-col tile
  const int i0  = tid >> 6;          // image 0..7 (+8k)
  const int sB0 = fi >> 1;           // sub-block of this lane's float4
  const int p1  = (r << 3) + ((fi & 1) << 2);   // pixel base, mult of 4
  const int lbase0 = sB0*SST + i0*IST + p1;     // +8*IST per k
  const int gc0 = col0 + (fi << 2);
  const size_t elt0 = (size_t)i0*IMG_STRIDE + (size_t)(row0+r)*WD + gc0;

  // ---- issue ALL x loads first (latency overlaps the minmax fold) ----
  float4 vv[4];
  #pragma unroll
  for (int k = 0; k < 4; ++k)
    vv[k] = *(const float4*)(x + elt0 + (size_t)(k << 3)*IMG_STRIDE);
  float lfe[4] = {0.0f, 0.0f, 0.0f, 0.0f};
  if (fi == 0 && col0){
    #pragma unroll
    for (int k = 0; k < 4; ++k)
      lfe[k] = x[elt0 + (size_t)(k << 3)*IMG_STRIDE - 1];
  }

  // ---- folded k_reduce: all threads reduce the 4096 partials ----
  float mnP = INFINITY, mxP = -INFINITY;
  {
    const float2* w2 = (const float2*)wsf;
    #pragma unroll
    for (int j = 0; j < 8; ++j){
      float2 p = w2[tid + (j << 9)];
      mnP = fminf(mnP, p.x); mxP = fmaxf(mxP, p.y);
    }
    #pragma unroll
    for (int off = 32; off; off >>= 1){
      mnP = fminf(mnP, __shfl_xor(mnP, off));
      mxP = fmaxf(mxP, __shfl_xor(mxP, off));
    }
    if ((tid & 63) == 0){ smm[tid >> 6] = mnP; smm[8 + (tid >> 6)] = mxP; }
  }
  __syncthreads();
  const float mn = fminf(fminf(fminf(smm[0], smm[1]), fminf(smm[2], smm[3])),
                         fminf(fminf(smm[4], smm[5]), fminf(smm[6], smm[7])));
  const float mx = fmaxf(fmaxf(fmaxf(smm[8], smm[9]), fmaxf(smm[10], smm[11])),
                         fmaxf(fmaxf(smm[12], smm[13]), fmaxf(smm[14], smm[15])));

  const bool  neq = (mx != mn);
  const float scale = neq ? (65535.0f / (mx - mn)) : 1.0f;
  const float sinv  = 1.0f / scale;
  const float moff  = neq ? mn : 0.0f;
  // lsb is an exact power of 2 -> division by it == multiplication by ilsb
  const float e1   = rintf(log2f(mx * (1.0f/32768.0f))) + 1.0f;
  const float lsb  = exp2f(e1);
  const float ilsb = exp2f(-e1);

  // ---- phase 1: delta + quantize/dequant -> dsh (1 b128 per k).
  float4 keep[4];
  #pragma unroll
  for (int k = 0; k < 4; ++k){
    float4 v = vv[k];
    float lf = __shfl_up(v.w, 1);
    if (fi == 0) lf = lfe[k];
    keep[k] = make_float4(lf, v.x, v.y, v.z);
    float d0 = v.x - lf, d1 = v.y - v.x, d2 = v.z - v.y, d3 = v.w - v.z;
    float q0, q1, q2, q3;
    if (neq){
      q0 = __fadd_rn(__fmul_rn(rintf((d0 - mn) * scale), sinv), moff);
      q1 = __fadd_rn(__fmul_rn(rintf((d1 - mn) * scale), sinv), moff);
      q2 = __fadd_rn(__fmul_rn(rintf((d2 - mn) * scale), sinv), moff);
      q3 = __fadd_rn(__fmul_rn(rintf((d3 - mn) * scale), sinv), moff);
    } else { q0 = d0; q1 = d1; q2 = d2; q3 = d3; }
    *(float4*)(dsh + lbase0 + k*(8*IST)) = make_float4(q0, q1, q2, q3);
  }
  __syncthreads();

  // ---- phase 2: normal matrix per sub-block (wave w -> sub-block w).
  // Full 64-lane butterfly leaves the sums in ALL lanes; each lane then
  // computes det/inv redundantly in registers and the image-invariant
  // projection vector b[0..2] for ITS pixel -> s_base (3 scalar writes,
  // conflict-free). Phase 3 only loads b (removes 72 VALU x 2 per thread
  // that was previously repeated for all 32 images).
  if (tid < 256){
    int s = tid >> 6;
    int p = tid & 63;
    float a0 = dsh[s*SST + 0*IST + p];   // image 0, pixel p (conflict-free)
    float a1 = dsh[s*SST + 1*IST + p];   // image 1, pixel p
    double s00 = (double)a0*a0, s01 = (double)a0*a1, s02 = a0;
    double s11 = (double)a1*a1, s12 = a1;
    float mx0 = a0, mn0 = a0, mx1 = a1, mn1 = a1;
    #pragma unroll
    for (int off = 32; off; off >>= 1){
      s00 += __shfl_xor(s00, off);
      s01 += __shfl_xor(s01, off);
      s02 += __shfl_xor(s02, off);
      s11 += __shfl_xor(s11, off);
      s12 += __shfl_xor(s12, off);
      mx0 = fmaxf(mx0, __shfl_xor(mx0, off));
      mn0 = fminf(mn0, __shfl_xor(mn0, off));
      mx1 = fmaxf(mx1, __shfl_xor(mx1, off));
      mn1 = fminf(mn1, __shfl_xor(mn1, off));
    }
    float i00,i01,i02,i10,i11,i12,i20,i21,i22;
    {
      double a = (float)s00, b = (float)s01, c = (float)s02;
      double d = (float)s11, e = (float)s12, f = 64.0;
      double c00 = d*f - e*e;
      double c01 = c*e - b*f;
      double c02 = b*e - c*d;
      double det = a*c00 + b*c01 + c*c02;
      if (det == 0.0){
        i00=1.f;i01=0.f;i02=0.f; i10=0.f;i11=1.f;i12=0.f; i20=0.f;i21=0.f;i22=1.f;
      } else {
        double id = 1.0/det;
        double c11 = a*f - c*c;
        double c12 = b*c - a*e;
        double c22 = a*d - b*b;
        i00=(float)(c00*id); i01=(float)(c01*id); i02=(float)(c02*id);
        i10=i01;             i11=(float)(c11*id); i12=(float)(c12*id);
        i20=i02;             i21=i12;             i22=(float)(c22*id);
      }
    }
    // b for this pixel (same op sequence as the old phase-3 inline compute)
    float b0 = __fadd_rn(__fmaf_rn(i01, a1, __fmul_rn(i00, a0)), i02);
    float b1 = __fadd_rn(__fmaf_rn(i11, a1, __fmul_rn(i10, a0)), i12);
    float b2 = __fadd_rn(__fmaf_rn(i21, a1, __fmul_rn(i20, a0)), i22);
    s_base[(s*3 + 0)*BST + p] = b0;
    s_base[(s*3 + 1)*BST + p] = b1;
    s_base[(s*3 + 2)*BST + p] = b2;
    if (p == 0)
      s_degen[s] = (((mx0 - mn0) < 1e-6f) && ((mx1 - mn1) < 1e-6f)) ? 1 : 0;
  }
  __syncthreads();

  // ---- phase 3: per-image fit; b loaded (broadcast), all-b128 staging.
  const int i_img = (tid >> 3) & 31;
  const int sub   = tid & 7;
  const int p0    = sub << 3;

  float dv[2][8];
  int ss[2];
  #pragma unroll
  for (int k = 0; k < 2; ++k){
    const int sB = ((tid >> 8) << 1) + k; ss[k] = sB;
    const int sb = sB*SST;
    float4 dlo = *(const float4*)(dsh + sb + i_img*IST + p0);
    float4 dhi = *(const float4*)(dsh + sb + i_img*IST + p0 + 4);
    float4 A0l = *(const float4*)(dsh + sb + 0*IST + p0);      // broadcast
    float4 A0h = *(const float4*)(dsh + sb + 0*IST + p0 + 4);
    float4 A1l = *(const float4*)(dsh + sb + 1*IST + p0);
    float4 A1h = *(const float4*)(dsh + sb + 1*IST + p0 + 4);
    float4 B0l = *(const float4*)(s_base + (sB*3 + 0)*BST + p0);
    float4 B0h = *(const float4*)(s_base + (sB*3 + 0)*BST + p0 + 4);
    float4 B1l = *(const float4*)(s_base + (sB*3 + 1)*BST + p0);
    float4 B1h = *(const float4*)(s_base + (sB*3 + 1)*BST + p0 + 4);
    float4 B2l = *(const float4*)(s_base + (sB*3 + 2)*BST + p0);
    float4 B2h = *(const float4*)(s_base + (sB*3 + 2)*BST + p0 + 4);
    float dva[8] = {dlo.x,dlo.y,dlo.z,dlo.w, dhi.x,dhi.y,dhi.z,dhi.w};
    float a0a[8] = {A0l.x,A0l.y,A0l.z,A0l.w, A0h.x,A0h.y,A0h.z,A0h.w};
    float a1a[8] = {A1l.x,A1l.y,A1l.z,A1l.w, A1h.x,A1h.y,A1h.z,A1h.w};
    float b0a[8] = {B0l.x,B0l.y,B0l.z,B0l.w, B0h.x,B0h.y,B0h.z,B0h.w};
    float b1a[8] = {B1l.x,B1l.y,B1l.z,B1l.w, B1h.x,B1h.y,B1h.z,B1h.w};
    float b2a[8] = {B2l.x,B2l.y,B2l.z,B2l.w, B2h.x,B2h.y,B2h.z,B2h.w};

    float pc0 = 0.f, pc1 = 0.f, pc2v = 0.f;
    #pragma unroll
    for (int c2 = 0; c2 < 8; ++c2){
      pc0  = __fmaf_rn(b0a[c2], dva[c2], pc0);
      pc1  = __fmaf_rn(b1a[c2], dva[c2], pc1);
      pc2v = __fmaf_rn(b2a[c2], dva[c2], pc2v);
    }
    pc0  += __shfl_xor(pc0, 1);  pc0  += __shfl_xor(pc0, 2);  pc0  += __shfl_xor(pc0, 4);
    pc1  += __shfl_xor(pc1, 1);  pc1  += __shfl_xor(pc1, 2);  pc1  += __shfl_xor(pc1, 4);
    pc2v += __shfl_xor(pc2v, 1); pc2v += __shfl_xor(pc2v, 2); pc2v += __shfl_xor(pc2v, 4);

    float r1v[8];
    float loss = 0.f;
    #pragma unroll
    for (int c2 = 0; c2 < 8; ++c2){
      float rv = __fadd_rn(__fmaf_rn(a1a[c2], pc1, __fmul_rn(a0a[c2], pc0)), pc2v);
      float r1 = __fmul_rn(rintf(__fmul_rn(rv, ilsb)), lsb);
      r1v[c2] = r1;
      float df = __fsub_rn(dva[c2], r1);
      loss = __fadd_rn(loss, __fmul_rn(df, df));
    }
    loss += __shfl_xor(loss, 1); loss += __shfl_xor(loss, 2); loss += __shfl_xor(loss, 4);
    const bool sel = (!s_degen[sB]) && (loss <= LOSS_THR_F);
    #pragma unroll
    for (int c2 = 0; c2 < 8; ++c2)
      dv[k][c2] = sel ? r1v[c2] : dva[c2];       // rr in registers
  }
  __syncthreads();                               // all reads done everywhere
  #pragma unroll
  for (int k = 0; k < 2; ++k){
    const int sb = ss[k]*SST + i_img*IST + p0;
    *(float4*)(dsh + sb)     = make_float4(dv[k][0], dv[k][1], dv[k][2], dv[k][3]);
    *(float4*)(dsh + sb + 4) = make_float4(dv[k][4], dv[k][5], dv[k][6], dv[k][7]);
  }
  __syncthreads();

  // ---- phase 4: coalesced epilogue, x_left from registers, b128 LDS reads,
  // NON-TEMPORAL stores: out is never re-read; keeping it out of L2/L3
  // stops it evicting x (134MB x + 134MB out > 256MB L3 -> thrash).
  #pragma unroll
  for (int k = 0; k < 4; ++k){
    const size_t elt = elt0 + (size_t)(k << 3)*IMG_STRIDE;
    float4 q = *(const float4*)(dsh + lbase0 + k*(8*IST));
    f4nt o;
    o.x = q.x + keep[k].x;
    o.y = q.y + keep[k].y;
    o.z = q.z + keep[k].z;
    o.w = q.w + keep[k].w;
    __builtin_nontemporal_store(o, (f4nt*)(out + elt));
  }
}

extern "C" void kernel_launch(void* const* d_in, const int* in_sizes, int n_in,
                              void* d_out, int out_size, void* d_ws, size_t ws_size,
                              hipStream_t stream) {
  const float* x = (const float*)d_in[0];
  float* out = (float*)d_out;
  float* wsf = (float*)d_ws;
  hipLaunchKernelGGL(k_minmax, dim3(MMX_BLOCKS), dim3(256), 0, stream, x, wsf);
  hipLaunchKernelGGL(k_main,   dim3(4096),       dim3(512), 0, stream, x, out, wsf);
}